// Round 7
// baseline (119.494 us; speedup 1.0000x reference)
//
#include <hip/hip_runtime.h>
#include <cstdint>
#include <cstddef>

#define ND 128
#define NK 1024
#define NROWS 8192
#define RANK 8

#define OFF_EMB 8192
#define OFF_CS  139264
#define OFF_EMA 140288

// workspace byte offsets
#define WSB_LTH 0u                    // Lt_hi  bf16 [8192][8][128]
#define WSB_LTM 16777216u             // Lt_mid bf16
#define WSB_U   33554432u             // u f32 [8192][8]
#define WSB_EH  33816576u             // E_hi  bf16 [1024][128]
#define WSB_EM  34078720u             // E_mid bf16
#define WSB_NTOT 34340864u
#define WSB_COUNTS 34341120u          // 1024 f32
#define WSB_DW  34345216u             // 131072 f32

typedef __attribute__((ext_vector_type(8))) short bf16x8;
typedef __attribute__((ext_vector_type(4))) float f32x4;

__device__ __forceinline__ short f2bf(float v) {
  union { float f; unsigned u; } a; a.f = v;
  unsigned r = a.u + 0x7fffu + ((a.u >> 16) & 1u);
  return (short)(r >> 16);
}
__device__ __forceinline__ float bf2f(short s) {
  union { unsigned u; float f; } a; a.u = ((unsigned)(unsigned short)s) << 16;
  return a.f;
}

__device__ __forceinline__ void gl_lds16(const short* gsrc, const short* lds) {
  __builtin_amdgcn_global_load_lds(
      (const __attribute__((address_space(1))) unsigned int*)gsrc,
      (__attribute__((address_space(3))) unsigned int*)lds, 16, 0, 0);
}

// ---------------------------------------------------------------------------
// kPre: b<1024: pivoted Cholesky (1 wave/n), emit Lt splits (bf16 h/m,
//       layout [n][r][i]) + u = L^T z (f32).
//       b 1024..1087: E -> Eh/Em bf16 splits (row-major [k][i]).
//       b 1088: ntot = 0.99*sum(cs) + 0.01*8192  (sum counts == N always)
//       b 1089..1153: zero counts+dw (33024 float4).
// ---------------------------------------------------------------------------
__global__ __launch_bounds__(512)
void kPre(const float* __restrict__ z, const float* __restrict__ G,
          const float* __restrict__ E, const float* __restrict__ cs,
          short* __restrict__ Lth, short* __restrict__ Ltm,
          float* __restrict__ uPack,
          short* __restrict__ Eh, short* __restrict__ Em,
          float* __restrict__ ntot, float* __restrict__ zeroReg)
{
  __shared__ float red[8];
  const int b   = blockIdx.x;
  const int tid = threadIdx.x;

  if (b < 1024) {
    const int wave = tid >> 6, lane = tid & 63;
    const int n = b * 8 + wave;
    const size_t gb = (size_t)n * (ND * ND);
    const int i0 = lane, i1 = lane + 64;
    float d0 = G[gb + (size_t)i0 * ND + i0];
    float d1 = G[gb + (size_t)i1 * ND + i1];
    float L0[RANK], L1[RANK];
    #pragma unroll
    for (int j = 0; j < RANK; ++j) {
      float mv; int p;
      if (d1 > d0) { mv = d1; p = i1; } else { mv = d0; p = i0; }
      #pragma unroll
      for (int off = 32; off; off >>= 1) {
        const float ov = __shfl_xor(mv, off);
        const int   op = __shfl_xor(p, off);
        if (ov > mv || (ov == mv && op < p)) { mv = ov; p = op; }
      }
      const float s = (mv > 1e-12f) ? (1.0f / sqrtf(mv)) : 0.0f;
      float c0 = G[gb + (size_t)p * ND + i0];
      float c1 = G[gb + (size_t)p * ND + i1];
      #pragma unroll
      for (int t = 0; t < j; ++t) {
        const float lsel = (p < 64) ? L0[t] : L1[t];
        const float lpt  = __shfl(lsel, p & 63);
        c0 -= L0[t] * lpt;
        c1 -= L1[t] * lpt;
      }
      const float l0 = c0 * s, l1 = c1 * s;
      L0[j] = l0; L1[j] = l1;
      d0 -= l0 * l0;
      d1 -= l1 * l1;
    }
    // Lt splits: [n][r][i]
    #pragma unroll
    for (int r = 0; r < RANK; ++r) {
      const size_t o0 = ((size_t)n * 8 + r) * 128 + i0;
      const size_t o1 = ((size_t)n * 8 + r) * 128 + i1;
      float v = L0[r];
      short h = f2bf(v);
      short m = f2bf(v - bf2f(h));
      Lth[o0] = h; Ltm[o0] = m;
      v = L1[r];
      h = f2bf(v);
      m = f2bf(v - bf2f(h));
      Lth[o1] = h; Ltm[o1] = m;
    }
    // u = L^T z
    const float z0 = z[(size_t)n * ND + i0];
    const float z1 = z[(size_t)n * ND + i1];
    float pu[RANK];
    #pragma unroll
    for (int r = 0; r < RANK; ++r) pu[r] = L0[r] * z0 + L1[r] * z1;
    #pragma unroll
    for (int off = 32; off; off >>= 1) {
      #pragma unroll
      for (int r = 0; r < RANK; ++r) pu[r] += __shfl_xor(pu[r], off);
    }
    if (lane == 0) {
      #pragma unroll
      for (int r = 0; r < RANK; ++r) uPack[(size_t)n * 8 + r] = pu[r];
    }
  } else if (b < 1088) {
    // E splits
    const int e4 = (b - 1024) * 2048 + tid * 4;
    const float4 v = *(const float4*)(E + e4);
    short h[4], m[4];
    const float vf[4] = {v.x, v.y, v.z, v.w};
    #pragma unroll
    for (int c = 0; c < 4; ++c) {
      h[c] = f2bf(vf[c]);
      m[c] = f2bf(vf[c] - bf2f(h[c]));
    }
    *(short4*)(Eh + e4) = make_short4(h[0], h[1], h[2], h[3]);
    *(short4*)(Em + e4) = make_short4(m[0], m[1], m[2], m[3]);
  } else if (b == 1088) {
    float s = cs[tid] + cs[tid + 512];
    #pragma unroll
    for (int off = 32; off; off >>= 1) s += __shfl_xor(s, off);
    const int wv = tid >> 6, lane = tid & 63;
    if (lane == 0) red[wv] = s;
    __syncthreads();
    if (tid == 0) {
      float t = 0.f;
      #pragma unroll
      for (int w = 0; w < 8; ++w) t += red[w];
      ntot[0] = fmaf(0.99f, t, 81.92f);
    }
  } else {
    const int idx4 = (b - 1089) * 512 + tid;
    if (idx4 < 33024) {
      float4 zv; zv.x = zv.y = zv.z = zv.w = 0.f;
      *(float4*)(zeroReg + (size_t)idx4 * 4) = zv;
    }
  }
}

// ---------------------------------------------------------------------------
// kDist: 8 n per block, 4 waves. Wave w: k-half (w&1), n-pairs {2*(w>>1), +1}.
// A = L^T (hoisted regs, 2 splits x 4 ksteps x 2 npairs), B = E tile (LDS,
// XOR-swizzled, double-buffered via global_load_lds with pre-swizzled src).
// K-loop uses counted vmcnt (never 0 mid-loop) + raw s_barriers so the
// next-tile DMA stays in flight across barriers (T3/T4, m201 pattern).
// ---------------------------------------------------------------------------
__global__ __launch_bounds__(256, 3)
void kDist(const float* __restrict__ z,
           const short* __restrict__ Lth, const short* __restrict__ Ltm,
           const float* __restrict__ uPack,
           const short* __restrict__ Eh, const short* __restrict__ Em,
           float* __restrict__ outIdxF, float* __restrict__ counts,
           float* __restrict__ dw)
{
  __shared__ __align__(16) short sEs[16384];   // 2 bufs x [2 kh][2 split][4096B]
  __shared__ float sU[64];
  __shared__ float sV[2][8];
  __shared__ int   sI[2][8];
  __shared__ int   sBI[8];

  const int tid  = threadIdx.x;
  const int wave = tid >> 6;
  const int lane = tid & 63;
  const int g    = wave >> 1;      // n-pair-group: owns npairs {2g, 2g+1}
  const int kh   = wave & 1;       // k-half
  const int base_n = blockIdx.x * 8;

  if (tid < 64) sU[tid] = uPack[(size_t)base_n * 8 + tid];

  // ---- hoist A-frags (L^T) to registers: [pp][ks], 2 splits ----
  bf16x8 Ah[2][4], Am[2][4];
  #pragma unroll
  for (int pp = 0; pp < 2; ++pp) {
    const int nloc = (g * 2 + pp) * 2 + ((lane & 15) >> 3);
    const size_t rowb = ((size_t)(base_n + nloc) * 8 + (lane & 7)) * 128 + ((lane >> 4) * 8);
    #pragma unroll
    for (int ks = 0; ks < 4; ++ks) {
      Ah[pp][ks] = *(const bf16x8*)(Lth + rowb + ks * 32);
      Am[pp][ks] = *(const bf16x8*)(Ltm + rowb + ks * 32);
    }
  }

  // ---- staging: load tile pair (it, 32+it) into buf d; 4 channels/wave ----
  const char* sBase = (const char*)sEs;
  auto STAGE = [&](int it, int d) {
    #pragma unroll
    for (int c = 0; c < 4; ++c) {
      const int ch    = wave * 4 + c;        // 0..15, wave-uniform
      const int khB   = ch >> 3;
      const int split = (ch >> 2) & 1;
      const int x = ((ch & 3) << 10) + (lane << 4);     // logical byte in 4KB tile
      const int P = x ^ (((x >> 8) & 7) << 4);          // pre-swizzled source
      const short* gbp = split ? Em : Eh;
      const short* gs = gbp + (size_t)(khB ? (32 + it) : it) * 2048 + (P >> 1);
      const short* ld = (const short*)(sBase + d * 16384 + ch * 1024);
      gl_lds16(gs, ld);
    }
  };

  // prologue: tile 0 staged + full drain once (also publishes sU, marks
  // A-frags available to the waitcnt pass -> no in-loop waits for them)
  STAGE(0, 0);
  __syncthreads();

  // per-lane u values for the 4 C rows, both npairs
  float uv0[4], uv1[4];
  #pragma unroll
  for (int reg = 0; reg < 4; ++reg) {
    const int nr = (lane >> 4) * 4 + reg;
    uv0[reg] = sU[((g * 2 + 0) * 2 + (nr >> 3)) * 8 + (nr & 7)];
    uv1[reg] = sU[((g * 2 + 1) * 2 + (nr >> 3)) * 8 + (nr & 7)];
  }

  const int x0 = ((lane & 15) << 8) + ((lane >> 4) << 4);
  const int xm = (lane & 7) << 4;

  float bv0 = 3.4e38f, bv1 = 3.4e38f;
  int   bi0 = 1 << 30, bi1 = 1 << 30;

  #pragma unroll 2
  for (int it = 0; it < 32; ++it) {
    if (it < 31) {
      STAGE(it + 1, (it + 1) & 1);
      // wait own tile-it loads only; tile-(it+1) DMA stays in flight
      asm volatile("s_waitcnt vmcnt(4)" ::: "memory");
    } else {
      asm volatile("s_waitcnt vmcnt(0)" ::: "memory");
    }
    __builtin_amdgcn_s_barrier();          // all waves: tile it landed
    asm volatile("" ::: "memory");

    const int bufoff = (it & 1) * 16384 + kh * 8192;
    f32x4 C0 = {0.f, 0.f, 0.f, 0.f};
    f32x4 C1 = {0.f, 0.f, 0.f, 0.f};
    #pragma unroll
    for (int ks = 0; ks < 4; ++ks) {
      const int sx = (x0 + (ks << 6)) ^ xm;
      const char* p = sBase + bufoff + sx;
      const bf16x8 Bh = *(const bf16x8*)(p);
      const bf16x8 Bm = *(const bf16x8*)(p + 4096);
      C0 = __builtin_amdgcn_mfma_f32_16x16x32_bf16(Ah[0][ks], Bh, C0, 0, 0, 0);
      C1 = __builtin_amdgcn_mfma_f32_16x16x32_bf16(Ah[1][ks], Bh, C1, 0, 0, 0);
      C0 = __builtin_amdgcn_mfma_f32_16x16x32_bf16(Ah[0][ks], Bm, C0, 0, 0, 0);
      C1 = __builtin_amdgcn_mfma_f32_16x16x32_bf16(Ah[1][ks], Bm, C1, 0, 0, 0);
      C0 = __builtin_amdgcn_mfma_f32_16x16x32_bf16(Am[0][ks], Bh, C0, 0, 0, 0);
      C1 = __builtin_amdgcn_mfma_f32_16x16x32_bf16(Am[1][ks], Bh, C1, 0, 0, 0);
    }
    asm volatile("" ::: "memory");
    __builtin_amdgcn_s_barrier();          // reads done -> buf reusable

    // register-only epilogue after the barrier (waves release buf sooner)
    float s0 = 0.f, s1 = 0.f;
    #pragma unroll
    for (int reg = 0; reg < 4; ++reg) {
      const float t0 = uv0[reg] - C0[reg]; s0 = fmaf(t0, t0, s0);
      const float t1 = uv1[reg] - C1[reg]; s1 = fmaf(t1, t1, s1);
    }
    s0 += __shfl_xor(s0, 16);
    s1 += __shfl_xor(s1, 16);
    const int k = ((kh << 5) + it) * 16 + (lane & 15);
    if (s0 < bv0 || (s0 == bv0 && k < bi0)) { bv0 = s0; bi0 = k; }
    if (s1 < bv1 || (s1 == bv1 && k < bi1)) { bv1 = s1; bi1 = k; }
  }

  // reduce over 16 k-columns (tie-break smaller k)
  #pragma unroll
  for (int off = 1; off < 16; off <<= 1) {
    const float o0 = __shfl_xor(bv0, off); const int j0 = __shfl_xor(bi0, off);
    if (o0 < bv0 || (o0 == bv0 && j0 < bi0)) { bv0 = o0; bi0 = j0; }
    const float o1 = __shfl_xor(bv1, off); const int j1 = __shfl_xor(bi1, off);
    if (o1 < bv1 || (o1 == bv1 && j1 < bi1)) { bv1 = o1; bi1 = j1; }
  }
  // lane 0: n-even results; lane 32: n-odd
  if (lane == 0) {
    sV[kh][(g * 2 + 0) * 2 + 0] = bv0; sI[kh][(g * 2 + 0) * 2 + 0] = bi0;
    sV[kh][(g * 2 + 1) * 2 + 0] = bv1; sI[kh][(g * 2 + 1) * 2 + 0] = bi1;
  }
  if (lane == 32) {
    sV[kh][(g * 2 + 0) * 2 + 1] = bv0; sI[kh][(g * 2 + 0) * 2 + 1] = bi0;
    sV[kh][(g * 2 + 1) * 2 + 1] = bv1; sI[kh][(g * 2 + 1) * 2 + 1] = bi1;
  }
  __syncthreads();

  if (tid < 8) {
    const float v0 = sV[0][tid], v1 = sV[1][tid];
    const int   j0 = sI[0][tid], j1 = sI[1][tid];
    const int   bi = (v1 < v0) ? j1 : j0;   // khalf0 k's all smaller: ties -> khalf0
    sBI[tid] = bi;
    outIdxF[base_n + tid] = (float)bi;
    atomicAdd(&counts[bi], 1.0f);
  }
  __syncthreads();

  // dw scatter: 32 threads x 4 dims per n
  const int nl = tid >> 5;
  const int d0 = (tid & 31) * 4;
  const int bk = sBI[nl];
  const float4 zv = *(const float4*)(z + (size_t)(base_n + nl) * ND + d0);
  atomicAdd(&dw[bk * ND + d0 + 0], zv.x);
  atomicAdd(&dw[bk * ND + d0 + 1], zv.y);
  atomicAdd(&dw[bk * ND + d0 + 2], zv.z);
  atomicAdd(&dw[bk * ND + d0 + 3], zv.w);
}

// ---------------------------------------------------------------------------
__global__ __launch_bounds__(256)
void kFinal(const float* __restrict__ cs, const float* __restrict__ ema,
            const float* __restrict__ counts, const float* __restrict__ dw,
            const float* __restrict__ ntot, float* __restrict__ outCs,
            float* __restrict__ outEmb, float* __restrict__ outEma)
{
  const int e = blockIdx.x * 256 + threadIdx.x;
  const int k = e >> 7;
  const float nt = ntot[0];
  const float v  = cs[k] * 0.99f + 0.01f * counts[k];
  const float sm = (v + 1e-5f) / (nt + 1024.0f * 1e-5f) * nt;
  const float nv = ema[e] * 0.99f + 0.01f * dw[e];
  outEma[e] = nv;
  outEmb[e] = nv / sm;
  if ((e & 127) == 0) outCs[k] = v;
}

extern "C" void kernel_launch(void* const* d_in, const int* in_sizes, int n_in,
                              void* d_out, int out_size, void* d_ws, size_t ws_size,
                              hipStream_t stream)
{
  const float* z  = (const float*)d_in[0];
  const float* G  = (const float*)d_in[1];
  const float* E  = (const float*)d_in[2];
  const float* cs = (const float*)d_in[3];
  const float* ew = (const float*)d_in[4];
  float* out = (float*)d_out;

  char* ws = (char*)d_ws;
  short* wLth = (short*)(ws + WSB_LTH);
  short* wLtm = (short*)(ws + WSB_LTM);
  float* wU   = (float*)(ws + WSB_U);
  short* wEh  = (short*)(ws + WSB_EH);
  short* wEm  = (short*)(ws + WSB_EM);
  float* wNtot   = (float*)(ws + WSB_NTOT);
  float* wCounts = (float*)(ws + WSB_COUNTS);
  float* wDw     = (float*)(ws + WSB_DW);

  kPre<<<1154, 512, 0, stream>>>(z, G, E, cs, wLth, wLtm, wU,
                                 wEh, wEm, wNtot, wCounts);
  kDist<<<1024, 256, 0, stream>>>(z, wLth, wLtm, wU, wEh, wEm,
                                  out, wCounts, wDw);
  kFinal<<<512, 256, 0, stream>>>(cs, ew, wCounts, wDw, wNtot,
                                  out + OFF_CS, out + OFF_EMB, out + OFF_EMA);
}

// Round 8
// 109.833 us; speedup vs baseline: 1.0880x; 1.0880x over previous
//
#include <hip/hip_runtime.h>
#include <cstdint>
#include <cstddef>

#define ND 128
#define NK 1024
#define NROWS 8192
#define RANK 8

#define OFF_EMB 8192
#define OFF_CS  139264
#define OFF_EMA 140288

// workspace byte offsets
#define WSB_LTH 0u                    // Lt_hi  bf16 [8192][8][128]
#define WSB_LTM 16777216u             // Lt_mid bf16
#define WSB_U   33554432u             // u f32 [8192][8]
#define WSB_EBH 33816576u             // E_hi  bf16, MFMA-fragment-major, 256KB
#define WSB_EBM 34078720u             // E_mid bf16, fragment-major
#define WSB_NTOT 34340864u
#define WSB_COUNTS 34341120u          // 1024 f32
#define WSB_DW  34345216u             // 131072 f32

typedef __attribute__((ext_vector_type(8))) short bf16x8;
typedef __attribute__((ext_vector_type(4))) float f32x4;

__device__ __forceinline__ short f2bf(float v) {
  union { float f; unsigned u; } a; a.f = v;
  unsigned r = a.u + 0x7fffu + ((a.u >> 16) & 1u);
  return (short)(r >> 16);
}
__device__ __forceinline__ float bf2f(short s) {
  union { unsigned u; float f; } a; a.u = ((unsigned)(unsigned short)s) << 16;
  return a.f;
}

// ---------------------------------------------------------------------------
// kPre: b<1024: pivoted Cholesky (1 wave/n), emit Lt splits (bf16 h/m,
//       layout [n][r][i]) + u = L^T z (f32).
//       b 1024..1087: E -> EBh/EBm bf16 splits in MFMA-fragment-major layout:
//         EB[(ktile*4+ks)*64 + lane] (8 shorts each), where for element (k,i):
//         ktile=k>>4, ks=i>>5, lane=(k&15)+(((i>>3)&3)<<4), e=i&7.
//       b 1088: ntot = 0.99*sum(cs) + 0.01*8192  (sum counts == N always)
//       b 1089..1153: zero counts+dw (33024 float4).
// ---------------------------------------------------------------------------
__global__ __launch_bounds__(512)
void kPre(const float* __restrict__ z, const float* __restrict__ G,
          const float* __restrict__ E, const float* __restrict__ cs,
          short* __restrict__ Lth, short* __restrict__ Ltm,
          float* __restrict__ uPack,
          short* __restrict__ EBh, short* __restrict__ EBm,
          float* __restrict__ ntot, float* __restrict__ zeroReg)
{
  __shared__ float red[8];
  const int b   = blockIdx.x;
  const int tid = threadIdx.x;

  if (b < 1024) {
    const int wave = tid >> 6, lane = tid & 63;
    const int n = b * 8 + wave;
    const size_t gb = (size_t)n * (ND * ND);
    const int i0 = lane, i1 = lane + 64;
    float d0 = G[gb + (size_t)i0 * ND + i0];
    float d1 = G[gb + (size_t)i1 * ND + i1];
    float L0[RANK], L1[RANK];
    #pragma unroll
    for (int j = 0; j < RANK; ++j) {
      float mv; int p;
      if (d1 > d0) { mv = d1; p = i1; } else { mv = d0; p = i0; }
      #pragma unroll
      for (int off = 32; off; off >>= 1) {
        const float ov = __shfl_xor(mv, off);
        const int   op = __shfl_xor(p, off);
        if (ov > mv || (ov == mv && op < p)) { mv = ov; p = op; }
      }
      const float s = (mv > 1e-12f) ? (1.0f / sqrtf(mv)) : 0.0f;
      float c0 = G[gb + (size_t)p * ND + i0];
      float c1 = G[gb + (size_t)p * ND + i1];
      #pragma unroll
      for (int t = 0; t < j; ++t) {
        const float lsel = (p < 64) ? L0[t] : L1[t];
        const float lpt  = __shfl(lsel, p & 63);
        c0 -= L0[t] * lpt;
        c1 -= L1[t] * lpt;
      }
      const float l0 = c0 * s, l1 = c1 * s;
      L0[j] = l0; L1[j] = l1;
      d0 -= l0 * l0;
      d1 -= l1 * l1;
    }
    // Lt splits: [n][r][i]
    #pragma unroll
    for (int r = 0; r < RANK; ++r) {
      const size_t o0 = ((size_t)n * 8 + r) * 128 + i0;
      const size_t o1 = ((size_t)n * 8 + r) * 128 + i1;
      float v = L0[r];
      short h = f2bf(v);
      short m = f2bf(v - bf2f(h));
      Lth[o0] = h; Ltm[o0] = m;
      v = L1[r];
      h = f2bf(v);
      m = f2bf(v - bf2f(h));
      Lth[o1] = h; Ltm[o1] = m;
    }
    // u = L^T z
    const float z0 = z[(size_t)n * ND + i0];
    const float z1 = z[(size_t)n * ND + i1];
    float pu[RANK];
    #pragma unroll
    for (int r = 0; r < RANK; ++r) pu[r] = L0[r] * z0 + L1[r] * z1;
    #pragma unroll
    for (int off = 32; off; off >>= 1) {
      #pragma unroll
      for (int r = 0; r < RANK; ++r) pu[r] += __shfl_xor(pu[r], off);
    }
    if (lane == 0) {
      #pragma unroll
      for (int r = 0; r < RANK; ++r) uPack[(size_t)n * 8 + r] = pu[r];
    }
  } else if (b < 1088) {
    // E splits -> fragment-major EB
    const int f4   = (b - 1024) * 512 + tid;   // float4 index, 0..32767
    const int flat = f4 * 4;
    const int k  = flat >> 7;
    const int i0 = flat & 127;
    const float4 v = *(const float4*)(E + flat);
    short h[4], m[4];
    const float vf[4] = {v.x, v.y, v.z, v.w};
    #pragma unroll
    for (int c = 0; c < 4; ++c) {
      h[c] = f2bf(vf[c]);
      m[c] = f2bf(vf[c] - bf2f(h[c]));
    }
    const int ktile = k >> 4, ks = i0 >> 5, hi = (i0 >> 3) & 3, e = i0 & 7;
    const size_t off = ((size_t)(ktile * 4 + ks) * 64 + ((k & 15) + (hi << 4))) * 8 + e;
    *(short4*)(EBh + off) = make_short4(h[0], h[1], h[2], h[3]);
    *(short4*)(EBm + off) = make_short4(m[0], m[1], m[2], m[3]);
  } else if (b == 1088) {
    float s = cs[tid] + cs[tid + 512];
    #pragma unroll
    for (int off = 32; off; off >>= 1) s += __shfl_xor(s, off);
    const int wv = tid >> 6, lane = tid & 63;
    if (lane == 0) red[wv] = s;
    __syncthreads();
    if (tid == 0) {
      float t = 0.f;
      #pragma unroll
      for (int w = 0; w < 8; ++w) t += red[w];
      ntot[0] = fmaf(0.99f, t, 81.92f);
    }
  } else {
    const int idx4 = (b - 1089) * 512 + tid;
    if (idx4 < 33024) {
      float4 zv; zv.x = zv.y = zv.z = zv.w = 0.f;
      *(float4*)(zeroReg + (size_t)idx4 * 4) = zv;
    }
  }
}

// ---------------------------------------------------------------------------
// kDist: one wave per 8 n, NO LDS, NO barriers. A = L^T hoisted (4 row-pairs
// x 4 ksteps x 2 splits = 128 VGPR). B fragments read directly from the
// fragment-major EB arrays (coalesced 1KB/instr, L2-resident broadcast),
// double-buffered in registers. 3-term split MFMA (hh+hm+mh), k ascending;
// wave-local argmin is the global argmin for its 8 n; fused scatter.
// ---------------------------------------------------------------------------
__global__ __launch_bounds__(256, 2)
void kDist(const float* __restrict__ z,
           const short* __restrict__ Lth, const short* __restrict__ Ltm,
           const float* __restrict__ uPack,
           const short* __restrict__ EBh, const short* __restrict__ EBm,
           float* __restrict__ outIdxF, float* __restrict__ counts,
           float* __restrict__ dw)
{
  const int lane = threadIdx.x & 63;
  const int wid  = (blockIdx.x * 256 + threadIdx.x) >> 6;   // 0..1023
  const int nb   = wid * 8;

  // ---- hoist A-frags (L^T), rows = (n-within-pair, r) ----
  bf16x8 Ah[4][4], Am[4][4];
  #pragma unroll
  for (int p = 0; p < 4; ++p) {
    const int nloc = p * 2 + ((lane & 15) >> 3);
    const size_t rowb = ((size_t)(nb + nloc) * 8 + (lane & 7)) * 128 + ((lane >> 4) * 8);
    #pragma unroll
    for (int ks = 0; ks < 4; ++ks) {
      Ah[p][ks] = *(const bf16x8*)(Lth + rowb + ks * 32);
      Am[p][ks] = *(const bf16x8*)(Ltm + rowb + ks * 32);
    }
  }
  // ---- u values for this lane's C rows ----
  float uv[4][4];
  #pragma unroll
  for (int p = 0; p < 4; ++p)
    #pragma unroll
    for (int reg = 0; reg < 4; ++reg) {
      const int nr = (lane >> 4) * 4 + reg;
      uv[p][reg] = uPack[(size_t)(nb + p * 2 + (nr >> 3)) * 8 + (nr & 7)];
    }

  float bv[4]; int bi[4];
  #pragma unroll
  for (int p = 0; p < 4; ++p) { bv[p] = 3.4e38f; bi[p] = 1 << 30; }

  bf16x8 B0h[4], B0m[4], B1h[4], B1m[4];

  auto LOADB = [&](bf16x8* Bh_, bf16x8* Bm_, int t_) {
    #pragma unroll
    for (int ks = 0; ks < 4; ++ks) {
      const size_t o = ((size_t)(t_ * 4 + ks) * 64 + lane) * 8;
      Bh_[ks] = *(const bf16x8*)(EBh + o);
      Bm_[ks] = *(const bf16x8*)(EBm + o);
    }
  };

  auto COMPUTE = [&](const bf16x8* Bh_, const bf16x8* Bm_, int t_) {
    f32x4 C[4];
    #pragma unroll
    for (int p = 0; p < 4; ++p) C[p] = (f32x4){0.f, 0.f, 0.f, 0.f};
    #pragma unroll
    for (int ks = 0; ks < 4; ++ks) {
      #pragma unroll
      for (int p = 0; p < 4; ++p)
        C[p] = __builtin_amdgcn_mfma_f32_16x16x32_bf16(Ah[p][ks], Bh_[ks], C[p], 0, 0, 0);
      #pragma unroll
      for (int p = 0; p < 4; ++p)
        C[p] = __builtin_amdgcn_mfma_f32_16x16x32_bf16(Ah[p][ks], Bm_[ks], C[p], 0, 0, 0);
      #pragma unroll
      for (int p = 0; p < 4; ++p)
        C[p] = __builtin_amdgcn_mfma_f32_16x16x32_bf16(Am[p][ks], Bh_[ks], C[p], 0, 0, 0);
    }
    const int kcol = t_ * 16 + (lane & 15);
    #pragma unroll
    for (int p = 0; p < 4; ++p) {
      float s = 0.f;
      #pragma unroll
      for (int reg = 0; reg < 4; ++reg) {
        const float d = uv[p][reg] - C[p][reg];
        s = fmaf(d, d, s);
      }
      s += __shfl_xor(s, 16);
      if (s < bv[p] || (s == bv[p] && kcol < bi[p])) { bv[p] = s; bi[p] = kcol; }
    }
  };

  LOADB(B0h, B0m, 0);
  for (int t = 0; t < 64; t += 2) {
    LOADB(B1h, B1m, t + 1);
    COMPUTE(B0h, B0m, t);
    if (t + 2 < 64) LOADB(B0h, B0m, t + 2);
    COMPUTE(B1h, B1m, t + 1);
  }

  // ---- reduce over 16 k-columns (tie-break smaller k) ----
  #pragma unroll
  for (int off = 1; off < 16; off <<= 1) {
    #pragma unroll
    for (int p = 0; p < 4; ++p) {
      const float ov = __shfl_xor(bv[p], off);
      const int   oi = __shfl_xor(bi[p], off);
      if (ov < bv[p] || (ov == bv[p] && oi < bi[p])) { bv[p] = ov; bi[p] = oi; }
    }
  }

  // lanes 0..31 hold even-n result of pair p; lanes 32..63 hold odd-n
  #pragma unroll
  for (int p = 0; p < 4; ++p) {
    const int kE = __shfl(bi[p], 0);
    const int kO = __shfl(bi[p], 32);
    const int nE = nb + 2 * p, nO = nE + 1;
    if (lane == 0)  { outIdxF[nE] = (float)kE; atomicAdd(&counts[kE], 1.0f); }
    if (lane == 32) { outIdxF[nO] = (float)kO; atomicAdd(&counts[kO], 1.0f); }
    const float zE0 = z[(size_t)nE * ND + lane];
    const float zE1 = z[(size_t)nE * ND + lane + 64];
    atomicAdd(&dw[kE * ND + lane],      zE0);
    atomicAdd(&dw[kE * ND + lane + 64], zE1);
    const float zO0 = z[(size_t)nO * ND + lane];
    const float zO1 = z[(size_t)nO * ND + lane + 64];
    atomicAdd(&dw[kO * ND + lane],      zO0);
    atomicAdd(&dw[kO * ND + lane + 64], zO1);
  }
}

// ---------------------------------------------------------------------------
__global__ __launch_bounds__(256)
void kFinal(const float* __restrict__ cs, const float* __restrict__ ema,
            const float* __restrict__ counts, const float* __restrict__ dw,
            const float* __restrict__ ntot, float* __restrict__ outCs,
            float* __restrict__ outEmb, float* __restrict__ outEma)
{
  const int e = blockIdx.x * 256 + threadIdx.x;
  const int k = e >> 7;
  const float nt = ntot[0];
  const float v  = cs[k] * 0.99f + 0.01f * counts[k];
  const float sm = (v + 1e-5f) / (nt + 1024.0f * 1e-5f) * nt;
  const float nv = ema[e] * 0.99f + 0.01f * dw[e];
  outEma[e] = nv;
  outEmb[e] = nv / sm;
  if ((e & 127) == 0) outCs[k] = v;
}

extern "C" void kernel_launch(void* const* d_in, const int* in_sizes, int n_in,
                              void* d_out, int out_size, void* d_ws, size_t ws_size,
                              hipStream_t stream)
{
  const float* z  = (const float*)d_in[0];
  const float* G  = (const float*)d_in[1];
  const float* E  = (const float*)d_in[2];
  const float* cs = (const float*)d_in[3];
  const float* ew = (const float*)d_in[4];
  float* out = (float*)d_out;

  char* ws = (char*)d_ws;
  short* wLth = (short*)(ws + WSB_LTH);
  short* wLtm = (short*)(ws + WSB_LTM);
  float* wU   = (float*)(ws + WSB_U);
  short* wEBh = (short*)(ws + WSB_EBH);
  short* wEBm = (short*)(ws + WSB_EBM);
  float* wNtot   = (float*)(ws + WSB_NTOT);
  float* wCounts = (float*)(ws + WSB_COUNTS);
  float* wDw     = (float*)(ws + WSB_DW);

  kPre<<<1154, 512, 0, stream>>>(z, G, E, cs, wLth, wLtm, wU,
                                 wEBh, wEBm, wNtot, wCounts);
  kDist<<<256, 256, 0, stream>>>(z, wLth, wLtm, wU, wEBh, wEBm,
                                 out, wCounts, wDw);
  kFinal<<<512, 256, 0, stream>>>(cs, ew, wCounts, wDw, wNtot,
                                  out + OFF_CS, out + OFF_EMB, out + OFF_EMA);
}